// Round 15
// baseline (64.422 us; speedup 1.0000x reference)
//
#include <hip/hip_runtime.h>

#define L  512
#define F  64
#define P  32
#define ZO 128
#define ICH 32   // i-chunk for k_z
#define JCH 16   // j-chunk for k_T

constexpr float EPS_LN   = 1e-10f;
constexpr float EPS_NORM = 1e-3f;

typedef float sf16 __attribute__((ext_vector_type(16)));

// ---------------------------------------------------------------------------
// Kernel 1: LayerNorm + two 64->32 projections. (~2us, frozen)
// ---------------------------------------------------------------------------
__global__ __launch_bounds__(256) void k_ln_proj(
    const float* __restrict__ M, const float* __restrict__ mask,
    const float* __restrict__ gamma, const float* __restrict__ beta,
    const float* __restrict__ Wa, const float* __restrict__ ba,
    const float* __restrict__ Wb, const float* __restrict__ bb,
    float* __restrict__ a, float* __restrict__ b) {
  __shared__ float y_lds[4][F];
  const int wave = threadIdx.x >> 6;
  const int lane = threadIdx.x & 63;
  const int row  = blockIdx.x * 4 + wave;

  float m = M[row * F + lane];
  float s = m;
  #pragma unroll
  for (int o = 32; o >= 1; o >>= 1) s += __shfl_xor(s, o);
  float mean = s * (1.0f / F);
  float d = m - mean;
  float v = d * d;
  #pragma unroll
  for (int o = 32; o >= 1; o >>= 1) v += __shfl_xor(v, o);
  float rstd = rsqrtf(v * (1.0f / F) + EPS_LN);
  float y = d * rstd * gamma[lane] + beta[lane];
  y_lds[wave][lane] = y;
  __syncthreads();

  const float mk = mask[row];
  const float* W    = (lane < P) ? Wa : Wb;
  const float* bias = (lane < P) ? ba : bb;
  const int p = lane & (P - 1);
  float acc = 0.f;
  #pragma unroll 8
  for (int f = 0; f < F; ++f) acc += y_lds[wave][f] * W[p * F + f];
  acc = (acc + bias[p]) * mk;
  float* outp = (lane < P) ? a : b;
  outp[row * P + p] = acc;
}

// ---------------------------------------------------------------------------
// Kernel 2: T[j][z][d] = sum_e b[j][e] * Wz[z*1024 + d*32 + e]  (~5us, frozen)
// ---------------------------------------------------------------------------
__global__ __launch_bounds__(256) void k_T(
    const float* __restrict__ b, const float* __restrict__ Wz,
    float* __restrict__ T) {
  const int seg = blockIdx.x * 256 + threadIdx.x;   // 0..4095
  const int j0  = blockIdx.y * JCH;

  float4 w[8];
  const float4* wp = (const float4*)(Wz + (size_t)seg * 32);
  #pragma unroll
  for (int q = 0; q < 8; ++q) w[q] = wp[q];

  #pragma unroll 2
  for (int jj = 0; jj < JCH; ++jj) {
    const float* __restrict__ br = b + (size_t)(j0 + jj) * P;  // uniform
    float acc0 = 0.f, acc1 = 0.f, acc2 = 0.f, acc3 = 0.f;
    #pragma unroll
    for (int q = 0; q < 8; ++q) {
      acc0 += w[q].x * br[q * 4 + 0];
      acc1 += w[q].y * br[q * 4 + 1];
      acc2 += w[q].z * br[q * 4 + 2];
      acc3 += w[q].w * br[q * 4 + 3];
    }
    T[(size_t)(j0 + jj) * (ZO * P) + seg] = (acc0 + acc1) + (acc2 + acc3);
  }
}

// ---------------------------------------------------------------------------
// Kernel 3: Z[i,j,z] = (sum_d a[i,d]*T[j,z,d] + bz[z]) / (eps + mask_i*mask_j)
// Round-15: R14 structure, ONE variable: occupancy 16 -> 32 waves/CU.
// Lane = ONE z (tw 8 float4 = 32 VGPR, half of R14) so total VGPR <= 64
// (enforced via __launch_bounds__(256,8)); wave = (j, z-half); block =
// 2 j x 2 z-half; grid (L/2, 16) = 4096 blocks. Mechanism under test:
// k_z scaled 84 -> ~46us with 2 -> 4 blocks/CU (R9->R8); each wave holds
// ~1 outstanding NT store, so 2x waves = 2x writes in flight. 256 B/wave
// stores (proven cost-neutral in R7). a-row + mask stay in SGPRs (R14).
// ---------------------------------------------------------------------------
__global__ __launch_bounds__(256, 8) void k_z(
    const float* __restrict__ a, const float* __restrict__ mask,
    const float* __restrict__ T, const float* __restrict__ bz,
    float* __restrict__ Z) {
  const int t    = threadIdx.x;
  const int lane = t & 63;
  const int w    = t >> 6;            // wave 0..3
  const int j    = blockIdx.x * 2 + (w >> 1);
  const int z    = (w & 1) * 64 + lane;
  const int i0   = blockIdx.y * ICH;

  // T fragment: row z of T[j] -> 32 consecutive floats (8 float4)
  float4 tw[8];
  const float4* tp = (const float4*)(T + ((size_t)j * ZO + z) * P);
  #pragma unroll
  for (int q = 0; q < 8; ++q) tw[q] = tp[q];

  const float bzv = bz[z];
  const float mj  = mask[j];          // wave-uniform

  const float* abase = a + (size_t)i0 * P;   // block-uniform
  const float* mbase = mask + i0;            // block-uniform
  float* outbase = Z + ((size_t)i0 * L + j) * ZO + z;

  sf16 loA, hiA, loB, hiB;
  float miA, miB;

#define SPREFETCH(LO, HI, MI, ROW)                                         \
  {                                                                        \
    unsigned offa  = (unsigned)(ROW) * 128u;                               \
    unsigned offa2 = offa + 64u;                                           \
    unsigned offm  = (unsigned)(ROW) * 4u;                                 \
    asm volatile("s_load_dwordx16 %0, %3, %5\n\t"                          \
                 "s_load_dwordx16 %1, %3, %6\n\t"                          \
                 "s_load_dword %2, %4, %7"                                 \
                 : "=&s"(LO), "=&s"(HI), "=&s"(MI)                         \
                 : "s"(abase), "s"(mbase), "s"(offa), "s"(offa2),          \
                   "s"(offm));                                             \
  }
#define SWAIT(LO, HI, MI)                                                  \
  asm volatile("s_waitcnt lgkmcnt(0)" : "+s"(LO), "+s"(HI), "+s"(MI));

  auto body = [&](const sf16& lo, const sf16& hi, float mi, int irow) {
    float x0 = 0.f, x1 = 0.f, x2 = 0.f, x3 = 0.f;
    #pragma unroll
    for (int q = 0; q < 8; ++q) {
      const float e0 = (q < 4) ? lo[4 * q + 0] : hi[4 * q - 16];
      const float e1 = (q < 4) ? lo[4 * q + 1] : hi[4 * q - 15];
      const float e2 = (q < 4) ? lo[4 * q + 2] : hi[4 * q - 14];
      const float e3 = (q < 4) ? lo[4 * q + 3] : hi[4 * q - 13];
      x0 += e0 * tw[q].x;
      x1 += e1 * tw[q].y;
      x2 += e2 * tw[q].z;
      x3 += e3 * tw[q].w;
    }
    const float inv = 1.0f / (EPS_NORM + mi * mj);
    const float o = ((x0 + x1) + (x2 + x3) + bzv) * inv;
    __builtin_nontemporal_store(o, outbase + (size_t)irow * (L * ZO));
  };

  SPREFETCH(loA, hiA, miA, 0)

  #pragma unroll 1
  for (int i = 0; i < ICH; i += 2) {
    SWAIT(loA, hiA, miA)
    SPREFETCH(loB, hiB, miB, i + 1)
    body(loA, hiA, miA, i);
    SWAIT(loB, hiB, miB)
    const int inx = (i + 2 < ICH) ? (i + 2) : 0;
    SPREFETCH(loA, hiA, miA, inx)
    body(loB, hiB, miB, i + 1);
  }
#undef SPREFETCH
#undef SWAIT
}

// ---------------------------------------------------------------------------
extern "C" void kernel_launch(void* const* d_in, const int* in_sizes, int n_in,
                              void* d_out, int out_size, void* d_ws, size_t ws_size,
                              hipStream_t stream) {
  const float* M     = (const float*)d_in[0];
  const float* mask  = (const float*)d_in[1];
  const float* gamma = (const float*)d_in[2];
  const float* beta  = (const float*)d_in[3];
  const float* Wa    = (const float*)d_in[4];
  const float* ba    = (const float*)d_in[5];
  const float* Wb    = (const float*)d_in[6];
  const float* bb    = (const float*)d_in[7];
  const float* Wz    = (const float*)d_in[8];
  const float* bz    = (const float*)d_in[9];

  float* Z = (float*)d_out;
  float* a = (float*)d_ws;            // 512*32 f32 = 64 KB
  float* b = a + L * P;               // 64 KB
  float* T = b + L * P;               // 8 MB

  k_ln_proj<<<L / 4, 256, 0, stream>>>(M, mask, gamma, beta, Wa, ba, Wb, bb, a, b);
  k_T<<<dim3((ZO * P) / 256, L / JCH), 256, 0, stream>>>(b, Wz, T);
  k_z<<<dim3(L / 2, L / ICH), 256, 0, stream>>>(a, mask, T, bz, Z);
}

// Round 16
// 41.758 us; speedup vs baseline: 1.5427x; 1.5427x over previous
//
#include <hip/hip_runtime.h>
#include <hip/hip_bf16.h>

#define L  512
#define F  64
#define P  32
#define ZO 128
#define JCH 16   // j-chunk for k_T

constexpr float EPS_LN   = 1e-10f;
constexpr float EPS_NORM = 1e-3f;

typedef short s16x8 __attribute__((ext_vector_type(8)));   // 8 bf16 (A/B frag)
typedef float f32x4 __attribute__((ext_vector_type(4)));   // C/D frag

// ---------------------------------------------------------------------------
// Kernel 1: LayerNorm + two 64->32 projections. Also emits bf16 copy of a.
// ---------------------------------------------------------------------------
__global__ __launch_bounds__(256) void k_ln_proj(
    const float* __restrict__ M, const float* __restrict__ mask,
    const float* __restrict__ gamma, const float* __restrict__ beta,
    const float* __restrict__ Wa, const float* __restrict__ ba,
    const float* __restrict__ Wb, const float* __restrict__ bb,
    float* __restrict__ a, float* __restrict__ b,
    __hip_bfloat16* __restrict__ abf) {
  __shared__ float y_lds[4][F];
  const int wave = threadIdx.x >> 6;
  const int lane = threadIdx.x & 63;
  const int row  = blockIdx.x * 4 + wave;

  float m = M[row * F + lane];
  float s = m;
  #pragma unroll
  for (int o = 32; o >= 1; o >>= 1) s += __shfl_xor(s, o);
  float mean = s * (1.0f / F);
  float d = m - mean;
  float v = d * d;
  #pragma unroll
  for (int o = 32; o >= 1; o >>= 1) v += __shfl_xor(v, o);
  float rstd = rsqrtf(v * (1.0f / F) + EPS_LN);
  float y = d * rstd * gamma[lane] + beta[lane];
  y_lds[wave][lane] = y;
  __syncthreads();

  const float mk = mask[row];
  const float* W    = (lane < P) ? Wa : Wb;
  const float* bias = (lane < P) ? ba : bb;
  const int p = lane & (P - 1);
  float acc = 0.f;
  #pragma unroll 8
  for (int f = 0; f < F; ++f) acc += y_lds[wave][f] * W[p * F + f];
  acc = (acc + bias[p]) * mk;
  if (lane < P) {
    a[row * P + p]   = acc;
    abf[row * P + p] = __float2bfloat16(acc);
  } else {
    b[row * P + p] = acc;
  }
}

// ---------------------------------------------------------------------------
// Kernel 2: T[j][z][d] = sum_e b[j][e] * Wz[z*1024 + d*32 + e], emitted bf16.
// (R5 structure; only the store dtype changed.)
// ---------------------------------------------------------------------------
__global__ __launch_bounds__(256) void k_T(
    const float* __restrict__ b, const float* __restrict__ Wz,
    __hip_bfloat16* __restrict__ Tbf) {
  const int seg = blockIdx.x * 256 + threadIdx.x;   // 0..4095
  const int j0  = blockIdx.y * JCH;

  float4 w[8];
  const float4* wp = (const float4*)(Wz + (size_t)seg * 32);
  #pragma unroll
  for (int q = 0; q < 8; ++q) w[q] = wp[q];

  #pragma unroll 2
  for (int jj = 0; jj < JCH; ++jj) {
    const float* __restrict__ br = b + (size_t)(j0 + jj) * P;  // uniform
    float acc0 = 0.f, acc1 = 0.f, acc2 = 0.f, acc3 = 0.f;
    #pragma unroll
    for (int q = 0; q < 8; ++q) {
      acc0 += w[q].x * br[q * 4 + 0];
      acc1 += w[q].y * br[q * 4 + 1];
      acc2 += w[q].z * br[q * 4 + 2];
      acc3 += w[q].w * br[q * 4 + 3];
    }
    Tbf[(size_t)(j0 + jj) * (ZO * P) + seg] =
        __float2bfloat16((acc0 + acc1) + (acc2 + acc3));
  }
}

// ---------------------------------------------------------------------------
// Kernel 3 (Round-16, MFMA): Z[i,n] = (sum_d abf[i,d]*Tbf[n,d] + bz)*inv,
// n = j*128+z. M=512, N=65536, K=32 == one mfma_f32_16x16x32_bf16 per
// 16x16 tile. Wave owns one n-tile (16 consecutive z of one j): B-frag
// loaded ONCE; loop 16 i-tiles: {A-frag dwordx4, MFMA, 4 mask loads,
// 4 f32 stores}. Fragment maps (m89-verified): A row=lane&15,
// k=(lane>>4)*8+e; B col=lane&15, same k; D col=lane&15,
// row=(lane>>4)*4+reg. ~35 VGPR -> 8 waves/SIMD; stores issue in bursts
// of 4 (fillBuffer-like deep store queues). Plain stores (R13: NT==plain;
// partial 64-B tile rows merge better in L2).
// ---------------------------------------------------------------------------
__global__ __launch_bounds__(256, 8) void k_z(
    const __hip_bfloat16* __restrict__ abf,  // [512][32]
    const float* __restrict__ mask,
    const __hip_bfloat16* __restrict__ Tbf,  // [65536][32]
    const float* __restrict__ bz,
    float* __restrict__ Z) {
  const int t     = threadIdx.x;
  const int lane  = t & 63;
  const int w     = t >> 6;
  const int ntile = blockIdx.x * 4 + w;      // 0..4095
  const int n0    = ntile * 16;
  const int j     = n0 >> 7;                 // n = j*128+z
  const int r16   = lane & 15;
  const int kg    = lane >> 4;               // k-group 0..3

  // B-frag: Tbf[n0+r16][kg*8 .. kg*8+7]  (8 contiguous bf16 = 16 B)
  const s16x8 bfrag =
      *(const s16x8*)((const short*)Tbf + (size_t)(n0 + r16) * P + kg * 8);

  const float mj  = mask[j];
  const float bzv = bz[(n0 & (ZO - 1)) + r16];

  for (int it = 0; it < 16; ++it) {
    const int i0 = blockIdx.y * 256 + it * 16;
    const s16x8 afrag =
        *(const s16x8*)((const short*)abf + (size_t)(i0 + r16) * P + kg * 8);
    f32x4 acc = {0.f, 0.f, 0.f, 0.f};
    acc = __builtin_amdgcn_mfma_f32_16x16x32_bf16(afrag, bfrag, acc, 0, 0, 0);

    float* zb = Z + (size_t)(i0 + kg * 4) * (L * ZO) + (n0 + r16);
    #pragma unroll
    for (int r = 0; r < 4; ++r) {
      const float mi  = mask[i0 + kg * 4 + r];
      const float inv = __builtin_amdgcn_rcpf(EPS_NORM + mi * mj);
      zb[(size_t)r * (L * ZO)] = (acc[r] + bzv) * inv;
    }
  }
}

// ---------------------------------------------------------------------------
extern "C" void kernel_launch(void* const* d_in, const int* in_sizes, int n_in,
                              void* d_out, int out_size, void* d_ws, size_t ws_size,
                              hipStream_t stream) {
  const float* M     = (const float*)d_in[0];
  const float* mask  = (const float*)d_in[1];
  const float* gamma = (const float*)d_in[2];
  const float* beta  = (const float*)d_in[3];
  const float* Wa    = (const float*)d_in[4];
  const float* ba    = (const float*)d_in[5];
  const float* Wb    = (const float*)d_in[6];
  const float* bb    = (const float*)d_in[7];
  const float* Wz    = (const float*)d_in[8];
  const float* bz    = (const float*)d_in[9];

  float* Z = (float*)d_out;
  float* a = (float*)d_ws;                         // 512*32 f32 = 64 KB
  float* b = a + L * P;                            // 64 KB
  __hip_bfloat16* Tbf = (__hip_bfloat16*)(b + L * P);        // 4 MB
  __hip_bfloat16* abf = Tbf + (size_t)L * ZO * P;            // 32 KB

  k_ln_proj<<<L / 4, 256, 0, stream>>>(M, mask, gamma, beta, Wa, ba, Wb, bb,
                                       a, b, abf);
  k_T<<<dim3((ZO * P) / 256, L / JCH), 256, 0, stream>>>(b, Wz, Tbf);
  k_z<<<dim3((L * ZO / 16) / 4, 2), 256, 0, stream>>>(abf, mask, Tbf, bz, Z);
}

// Round 17
// 41.261 us; speedup vs baseline: 1.5613x; 1.0120x over previous
//
#include <hip/hip_runtime.h>
#include <hip/hip_bf16.h>

#define L  512
#define F  64
#define P  32
#define ZO 128
#define JCH 16   // j-chunk for k_T
#define LZ (L * ZO)

constexpr float EPS_LN   = 1e-10f;
constexpr float EPS_NORM = 1e-3f;

typedef short s16x8 __attribute__((ext_vector_type(8)));   // 8 bf16 (A/B frag)
typedef float f32x4 __attribute__((ext_vector_type(4)));   // C/D frag

// ---------------------------------------------------------------------------
// Kernel 1: LayerNorm + two 64->32 projections; also emits bf16 copy of a.
// (~2us, frozen)
// ---------------------------------------------------------------------------
__global__ __launch_bounds__(256) void k_ln_proj(
    const float* __restrict__ M, const float* __restrict__ mask,
    const float* __restrict__ gamma, const float* __restrict__ beta,
    const float* __restrict__ Wa, const float* __restrict__ ba,
    const float* __restrict__ Wb, const float* __restrict__ bb,
    float* __restrict__ a, float* __restrict__ b,
    __hip_bfloat16* __restrict__ abf) {
  __shared__ float y_lds[4][F];
  const int wave = threadIdx.x >> 6;
  const int lane = threadIdx.x & 63;
  const int row  = blockIdx.x * 4 + wave;

  float m = M[row * F + lane];
  float s = m;
  #pragma unroll
  for (int o = 32; o >= 1; o >>= 1) s += __shfl_xor(s, o);
  float mean = s * (1.0f / F);
  float d = m - mean;
  float v = d * d;
  #pragma unroll
  for (int o = 32; o >= 1; o >>= 1) v += __shfl_xor(v, o);
  float rstd = rsqrtf(v * (1.0f / F) + EPS_LN);
  float y = d * rstd * gamma[lane] + beta[lane];
  y_lds[wave][lane] = y;
  __syncthreads();

  const float mk = mask[row];
  const float* W    = (lane < P) ? Wa : Wb;
  const float* bias = (lane < P) ? ba : bb;
  const int p = lane & (P - 1);
  float acc = 0.f;
  #pragma unroll 8
  for (int f = 0; f < F; ++f) acc += y_lds[wave][f] * W[p * F + f];
  acc = (acc + bias[p]) * mk;
  if (lane < P) {
    a[row * P + p]   = acc;
    abf[row * P + p] = __float2bfloat16(acc);
  } else {
    b[row * P + p] = acc;
  }
}

// ---------------------------------------------------------------------------
// Kernel 2: T[j][z][d] = sum_e b[j][e] * Wz[z*1024 + d*32 + e], bf16 out.
// (~4.5us, frozen)
// ---------------------------------------------------------------------------
__global__ __launch_bounds__(256) void k_T(
    const float* __restrict__ b, const float* __restrict__ Wz,
    __hip_bfloat16* __restrict__ Tbf) {
  const int seg = blockIdx.x * 256 + threadIdx.x;   // 0..4095
  const int j0  = blockIdx.y * JCH;

  float4 w[8];
  const float4* wp = (const float4*)(Wz + (size_t)seg * 32);
  #pragma unroll
  for (int q = 0; q < 8; ++q) w[q] = wp[q];

  #pragma unroll 2
  for (int jj = 0; jj < JCH; ++jj) {
    const float* __restrict__ br = b + (size_t)(j0 + jj) * P;  // uniform
    float acc0 = 0.f, acc1 = 0.f, acc2 = 0.f, acc3 = 0.f;
    #pragma unroll
    for (int q = 0; q < 8; ++q) {
      acc0 += w[q].x * br[q * 4 + 0];
      acc1 += w[q].y * br[q * 4 + 1];
      acc2 += w[q].z * br[q * 4 + 2];
      acc3 += w[q].w * br[q * 4 + 3];
    }
    Tbf[(size_t)(j0 + jj) * (ZO * P) + seg] =
        __float2bfloat16((acc0 + acc1) + (acc2 + acc3));
  }
}

// ---------------------------------------------------------------------------
// Kernel 3 (Round-17): MFMA GEMM, roles swapped vs R16. Wave = ONE i-tile
// (A-frag loaded once) x 16 consecutive n-tiles (B-frag per iter from
// L3-resident Tbf). All scalars hoisted: mi as float4, mj0/mj1, 8 bz vals,
// inv precomputed for both j halves -> per-iter vmem = 1 B-frag + 4 stores
// (was 9 in R16). Successive stores per row walk consecutive 64-B chunks,
// so the wave itself fills 256-B+ L2 lines. Block = 4 waves = 4 adjacent
// n-groups of one i-tile (16 rows x 1024 contiguous n per block).
// Fragment maps (R16 hardware-verified): A row=lane&15, k=(lane>>4)*8+e;
// B col=lane&15 (->n), same k; D col=lane&15, row=(lane>>4)*4+reg (->i).
// ---------------------------------------------------------------------------
__global__ __launch_bounds__(256, 8) void k_z(
    const __hip_bfloat16* __restrict__ abf,  // [512][32]
    const float* __restrict__ mask,
    const __hip_bfloat16* __restrict__ Tbf,  // [65536][32]
    const float* __restrict__ bz,
    float* __restrict__ Z) {
  const int t    = threadIdx.x;
  const int lane = t & 63;
  const int w    = t >> 6;             // n-group within block
  const int r16  = lane & 15;
  const int kg   = lane >> 4;          // k-group / i-row group
  const int i0   = blockIdx.y * 16;    // i-tile base
  const int ng   = blockIdx.x * 4 + w; // 0..255, 256 n each
  const int n0   = ng * 256;           // multiple of 256

  // A-frag: abf[i0+r16][kg*8..+7] -- once per wave
  const s16x8 afrag =
      *(const s16x8*)((const short*)abf + (size_t)(i0 + r16) * P + kg * 8);

  // mask rows this lane stores (i = i0 + kg*4 + r), one float4
  const float4 mi4 = *(const float4*)(mask + i0 + kg * 4);
  // two j values span the 256-n window
  const float mj0 = mask[n0 >> 7];
  const float mj1 = mask[(n0 >> 7) + 1];
  float inv0[4], inv1[4];
  inv0[0] = __builtin_amdgcn_rcpf(EPS_NORM + mi4.x * mj0);
  inv0[1] = __builtin_amdgcn_rcpf(EPS_NORM + mi4.y * mj0);
  inv0[2] = __builtin_amdgcn_rcpf(EPS_NORM + mi4.z * mj0);
  inv0[3] = __builtin_amdgcn_rcpf(EPS_NORM + mi4.w * mj0);
  inv1[0] = __builtin_amdgcn_rcpf(EPS_NORM + mi4.x * mj1);
  inv1[1] = __builtin_amdgcn_rcpf(EPS_NORM + mi4.y * mj1);
  inv1[2] = __builtin_amdgcn_rcpf(EPS_NORM + mi4.z * mj1);
  inv1[3] = __builtin_amdgcn_rcpf(EPS_NORM + mi4.w * mj1);

  // bz values this lane needs: z = (q&7)*16 + r16
  float bzr[8];
  #pragma unroll
  for (int k2 = 0; k2 < 8; ++k2) bzr[k2] = bz[k2 * 16 + r16];

  const short* tb = (const short*)Tbf + (size_t)(n0 + r16) * P + kg * 8;
  float* zb = Z + (size_t)(i0 + kg * 4) * LZ + n0 + r16;

  #pragma unroll
  for (int q = 0; q < 16; ++q) {
    const s16x8 bfrag = *(const s16x8*)(tb + (size_t)q * 16 * P);
    f32x4 acc = {0.f, 0.f, 0.f, 0.f};
    acc = __builtin_amdgcn_mfma_f32_16x16x32_bf16(afrag, bfrag, acc, 0, 0, 0);
    const float bzv = bzr[q & 7];
    float* zq = zb + q * 16;
    if (q < 8) {
      zq[(size_t)0 * LZ] = (acc[0] + bzv) * inv0[0];
      zq[(size_t)1 * LZ] = (acc[1] + bzv) * inv0[1];
      zq[(size_t)2 * LZ] = (acc[2] + bzv) * inv0[2];
      zq[(size_t)3 * LZ] = (acc[3] + bzv) * inv0[3];
    } else {
      zq[(size_t)0 * LZ] = (acc[0] + bzv) * inv1[0];
      zq[(size_t)1 * LZ] = (acc[1] + bzv) * inv1[1];
      zq[(size_t)2 * LZ] = (acc[2] + bzv) * inv1[2];
      zq[(size_t)3 * LZ] = (acc[3] + bzv) * inv1[3];
    }
  }
}

// ---------------------------------------------------------------------------
extern "C" void kernel_launch(void* const* d_in, const int* in_sizes, int n_in,
                              void* d_out, int out_size, void* d_ws, size_t ws_size,
                              hipStream_t stream) {
  const float* M     = (const float*)d_in[0];
  const float* mask  = (const float*)d_in[1];
  const float* gamma = (const float*)d_in[2];
  const float* beta  = (const float*)d_in[3];
  const float* Wa    = (const float*)d_in[4];
  const float* ba    = (const float*)d_in[5];
  const float* Wb    = (const float*)d_in[6];
  const float* bb    = (const float*)d_in[7];
  const float* Wz    = (const float*)d_in[8];
  const float* bz    = (const float*)d_in[9];

  float* Z = (float*)d_out;
  float* a = (float*)d_ws;                         // 512*32 f32 = 64 KB
  float* b = a + L * P;                            // 64 KB
  __hip_bfloat16* Tbf = (__hip_bfloat16*)(b + L * P);        // 4 MB
  __hip_bfloat16* abf = Tbf + (size_t)L * ZO * P;            // 32 KB

  k_ln_proj<<<L / 4, 256, 0, stream>>>(M, mask, gamma, beta, Wa, ba, Wb, bb,
                                       a, b, abf);
  k_T<<<dim3((ZO * P) / 256, L / JCH), 256, 0, stream>>>(b, Wz, Tbf);
  k_z<<<dim3(64, 32), 256, 0, stream>>>(abf, mask, Tbf, bz, Z);
}